// Round 19
// baseline (73.054 us; speedup 1.0000x reference)
//
#include <hip/hip_runtime.h>
#include <hip/hip_bf16.h>

#define BDIM 256
#define NPTS (8 * 2048)           // B*N
#define CC 128
#define DD 32
#define FF 512
#define NN 2048
#define SCALE 0.08838834764831845f   // 1/sqrt(128)

typedef float f32x4 __attribute__((ext_vector_type(4)));
typedef short s16x8 __attribute__((ext_vector_type(8)));
typedef unsigned short ushort_t;

__device__ __forceinline__ ushort_t bf16r(float x) {
    __hip_bfloat16 h = __float2bfloat16(x);
    return *reinterpret_cast<ushort_t*>(&h);
}
__device__ __forceinline__ float bf16tof(ushort_t u) {
    unsigned v = ((unsigned)u) << 16;
    return *reinterpret_cast<float*>(&v);
}
__device__ __forceinline__ unsigned pack2(float a, float b) {
    return ((unsigned)bf16r(b) << 16) | (unsigned)bf16r(a);
}

// ---------------- kernel 0: all weights f32 -> bf16, one launch ----------------
__global__ void k_cvt_all(const float* __restrict__ W1, const float* __restrict__ W2,
                          const float* __restrict__ Wq, const float* __restrict__ Wk,
                          const float* __restrict__ Wv, const float* __restrict__ Wt,
                          ushort_t* __restrict__ dst) {
    int i = blockIdx.x * BDIM + threadIdx.x;     // float4 index, 43008 total
    const float* src; int off;
    if (i < 16384)      { src = W1; off = 0; }
    else if (i < 32768) { src = W2; off = 16384; }
    else if (i < 33792) { src = Wq; off = 32768; }
    else if (i < 34816) { src = Wk; off = 33792; }
    else if (i < 38912) { src = Wv; off = 34816; }
    else                { src = Wt; off = 38912; }
    float4 v = ((const float4*)src)[i - off];
    *(uint2*)(dst + (long)i * 4) = make_uint2(pack2(v.x, v.y), pack2(v.z, v.w));
}

// ---------------- kernel 1: MFMA q/k/vT projection (XCD-swizzled: b = bid&7) ----------------
__global__ __launch_bounds__(256) void k_proj(
        const float* __restrict__ x, const ushort_t* __restrict__ Wb,
        const float* __restrict__ bv,
        ushort_t* __restrict__ qg, ushort_t* __restrict__ kg,
        ushort_t* __restrict__ vTg) {
    __shared__ ushort_t xs[32][136];
    __shared__ ushort_t qks[32][72];    // q cols 0-31, k cols 32-63
    __shared__ ushort_t vs[32][136];
    int b = blockIdx.x & 7;
    int n0 = (blockIdx.x >> 3) * 32;
    long base = (long)b * NN + n0;
    int t = threadIdx.x, w = t >> 6, l = t & 63, a = l & 15, g = l >> 4;
    {
        const float4* xg4 = (const float4*)(x + base * CC);
        #pragma unroll
        for (int rep = 0; rep < 4; ++rep) {
            int i = rep * BDIM + t;
            float4 v4 = xg4[i];
            int p = i >> 5, c4 = (i & 31) * 4;
            *(uint2*)&xs[p][c4] = make_uint2(pack2(v4.x, v4.y), pack2(v4.z, v4.w));
        }
    }
    s16x8 bF[3][4];
    #pragma unroll
    for (int ct = 0; ct < 3; ++ct) {
        int ctg = w * 3 + ct;
        #pragma unroll
        for (int ki = 0; ki < 4; ++ki)
            bF[ct][ki] = *(const s16x8*)(Wb + ((long)(ctg * 16 + a)) * CC + ki * 32 + g * 8);
    }
    __syncthreads();
    #pragma unroll
    for (int rt = 0; rt < 2; ++rt) {
        s16x8 aF[4];
        #pragma unroll
        for (int ki = 0; ki < 4; ++ki)
            aF[ki] = *(const s16x8*)&xs[rt * 16 + a][ki * 32 + g * 8];
        #pragma unroll
        for (int ct = 0; ct < 3; ++ct) {
            f32x4 acc = (f32x4){0.f, 0.f, 0.f, 0.f};
            #pragma unroll
            for (int ki = 0; ki < 4; ++ki)
                acc = __builtin_amdgcn_mfma_f32_16x16x32_bf16(aF[ki], bF[ct][ki], acc, 0, 0, 0);
            int ctg = w * 3 + ct;
            int oc = ctg * 16 + a;
            float bias = (oc >= 64) ? bv[oc - 64] : 0.f;
            #pragma unroll
            for (int r = 0; r < 4; ++r) {
                int p = rt * 16 + g * 4 + r;
                float val = acc[r] + bias;
                if (oc < 64) qks[p][oc] = bf16r(val);
                else         vs[p][oc - 64] = bf16r(val);
            }
        }
    }
    __syncthreads();
    {
        int p = t >> 3, c = (t & 7) * 4;
        *(uint2*)(qg + (base + p) * DD + c) = *(const uint2*)&qks[p][c];
        *(uint2*)(kg + (base + p) * DD + c) = *(const uint2*)&qks[p][32 + c];
    }
    #pragma unroll
    for (int rep = 0; rep < 2; ++rep) {
        int i = rep * BDIM + t;
        int c = i & 127, nch = i >> 7;
        int p0 = nch * 8;
        uint4 r;
        r.x = (unsigned)vs[p0+0][c] | ((unsigned)vs[p0+1][c] << 16);
        r.y = (unsigned)vs[p0+2][c] | ((unsigned)vs[p0+3][c] << 16);
        r.z = (unsigned)vs[p0+4][c] | ((unsigned)vs[p0+5][c] << 16);
        r.w = (unsigned)vs[p0+6][c] | ((unsigned)vs[p0+7][c] << 16);
        *(uint4*)(vTg + ((long)(b * CC + c)) * NN + n0 + p0) = r;
    }
}

// ---------------- kernel 2: MFMA row softmax sums (XCD-swizzled: b = bid&7) ----------------
__global__ __launch_bounds__(256) void k_rowstats(
        const ushort_t* __restrict__ qg, const ushort_t* __restrict__ kg,
        float* __restrict__ rowinv) {
    __shared__ float ps[4][64];
    int b = blockIdx.x & 7;
    int nt = (blockIdx.x >> 3) * 64;
    int t = threadIdx.x, w = t >> 6, l = t & 63, a = l & 15, g = l >> 4;
    s16x8 qA[4];
    #pragma unroll
    for (int s = 0; s < 4; ++s)
        qA[s] = *(const s16x8*)(qg + ((long)(b * NN + nt + s*16 + a)) * DD + g*8);
    float sm[16];
    #pragma unroll
    for (int i = 0; i < 16; ++i) sm[i] = 0.f;
    s16x8 kB = *(const s16x8*)(kg + ((long)(b * NN + w * 16 + a)) * DD + g*8);
    for (int it = 0; it < 32; ++it) {
        s16x8 kBn;
        if (it < 31)
            kBn = *(const s16x8*)(kg + ((long)(b * NN + ((it+1)*4 + w)*16 + a)) * DD + g*8);
        #pragma unroll
        for (int s = 0; s < 4; ++s) {
            f32x4 D = (f32x4){0.f, 0.f, 0.f, 0.f};
            D = __builtin_amdgcn_mfma_f32_16x16x32_bf16(qA[s], kB, D, 0, 0, 0);
            #pragma unroll
            for (int r = 0; r < 4; ++r)
                sm[s * 4 + r] += __expf(D[r] * SCALE);
        }
        kB = kBn;
    }
    #pragma unroll
    for (int off = 1; off < 16; off <<= 1)
        #pragma unroll
        for (int ix = 0; ix < 16; ++ix)
            sm[ix] += __shfl_xor(sm[ix], off, 64);
    if (a == 0) {
        #pragma unroll
        for (int s = 0; s < 4; ++s)
            #pragma unroll
            for (int r = 0; r < 4; ++r)
                ps[w][s * 16 + g * 4 + r] = sm[s * 4 + r];
    }
    __syncthreads();
    if (t < 64) {
        float S = ps[0][t] + ps[1][t] + ps[2][t] + ps[3][t];
        rowinv[(long)b * NN + nt + t] = 1.f / S;
    }
}

// ---------------- kernel 3: MFMA PV (XCD-swizzled, staged-vT dbuf, T5 setprio) + tproj epilogue ----------------
// grid: 512 blocks x 512 thr. LDS 41472 B: vTs[2][128][72] @0 | pT[32][72] @36864.
__global__ __launch_bounds__(512) void k_pv(
        const ushort_t* __restrict__ qg, const ushort_t* __restrict__ kg,
        const ushort_t* __restrict__ vTg, const float* __restrict__ rowinv,
        const float* __restrict__ x, const ushort_t* __restrict__ Wtb,
        const float* __restrict__ bt,
        const float* __restrict__ g1, const float* __restrict__ b1,
        const float* __restrict__ m1, const float* __restrict__ v1,
        ushort_t* __restrict__ hb) {
    __shared__ __align__(16) char arena[41472];
    auto vTs = (ushort_t (*)[128][72])(arena);          // [2][128][72]
    auto pT  = (ushort_t (*)[72])(arena + 36864);       // [32][72]
    int b = blockIdx.x & 7;
    int m0 = (blockIdx.x >> 3) * 32;
    int t = threadIdx.x, w = t >> 6, l = t & 63, a = l & 15, g = l >> 4;
    int nsub = w & 3, msub = w >> 2;
    const ushort_t* vTb = vTg + (long)b * CC * NN;
    // per-wave constant K frag
    s16x8 kf = *(const s16x8*)(kg + ((long)(b * NN + m0 + msub * 16 + a)) * DD + g * 8);
    // direct-prefetch bases
    const ushort_t* qrow = qg + ((long)(b * NN + nsub * 16 + a)) * DD + g * 8;
    const float*    rrow = rowinv + (long)b * NN + nsub * 16 + g * 4;
    // vT staging indices: 2 reps x (64 rows x 8 uint4)
    int sc = t >> 3;            // row 0..63 (rep adds +64)
    int sj = (t & 7) * 8;       // ushort col offset
    // prologue: stage tile 0, load E-frags for tile 0
    s16x8 qf_c = *(const s16x8*)qrow;
    float4 rr_c = *(const float4*)rrow;
    {
        uint4 v0 = *(const uint4*)(vTb + (long)sc * NN + sj);
        uint4 v1 = *(const uint4*)(vTb + (long)(64 + sc) * NN + sj);
        *(uint4*)&vTs[0][sc][sj] = v0;
        *(uint4*)&vTs[0][64 + sc][sj] = v1;
    }
    f32x4 acc[2];
    acc[0] = (f32x4){0.f, 0.f, 0.f, 0.f};
    acc[1] = (f32x4){0.f, 0.f, 0.f, 0.f};
    int cur = 0;
    __syncthreads();                       // vTs[0] ready
    s16x8 qf_n; float4 rr_n; uint4 vsr0, vsr1;
    for (int it = 0; it < 32; ++it) {
        long ntn = (long)(it + 1) * 64;
        if (it < 31) {                     // issue tile it+1 loads (land during E+PV)
            vsr0 = *(const uint4*)(vTb + (long)sc * NN + ntn + sj);
            vsr1 = *(const uint4*)(vTb + (long)(64 + sc) * NN + ntn + sj);
            qf_n = *(const s16x8*)(qrow + ntn * DD);
            rr_n = *(const float4*)(rrow + ntn);
        }
        // E phase on tile it -> pT
        {
            __builtin_amdgcn_s_setprio(1);
            f32x4 e = (f32x4){0.f, 0.f, 0.f, 0.f};
            e = __builtin_amdgcn_mfma_f32_16x16x32_bf16(qf_c, kf, e, 0, 0, 0);
            __builtin_amdgcn_s_setprio(0);
            float p0 = __expf(e[0] * SCALE) * rr_c.x;
            float p1 = __expf(e[1] * SCALE) * rr_c.y;
            float p2 = __expf(e[2] * SCALE) * rr_c.z;
            float p3 = __expf(e[3] * SCALE) * rr_c.w;
            *(uint2*)&pT[msub * 16 + a][nsub * 16 + g * 4] =
                make_uint2(pack2(p0, p1), pack2(p2, p3));
        }
        __syncthreads();                   // pT ready (vTs[cur] still valid)
        // PV phase on tile it
        __builtin_amdgcn_s_setprio(1);
        #pragma unroll
        for (int k2 = 0; k2 < 2; ++k2) {
            s16x8 A0 = *(const s16x8*)&pT[a][k2 * 32 + g * 8];
            s16x8 A1 = *(const s16x8*)&pT[16 + a][k2 * 32 + g * 8];
            s16x8 Bf = *(const s16x8*)&vTs[cur][w * 16 + a][k2 * 32 + g * 8];
            acc[0] = __builtin_amdgcn_mfma_f32_16x16x32_bf16(A0, Bf, acc[0], 0, 0, 0);
            acc[1] = __builtin_amdgcn_mfma_f32_16x16x32_bf16(A1, Bf, acc[1], 0, 0, 0);
        }
        __builtin_amdgcn_s_setprio(0);
        if (it < 31) {                     // write staged tile into other buffer
            *(uint4*)&vTs[cur ^ 1][sc][sj] = vsr0;
            *(uint4*)&vTs[cur ^ 1][64 + sc][sj] = vsr1;
        }
        qf_c = qf_n; rr_c = rr_n;
        __syncthreads();                   // vTs[cur^1] ready; pT consumed
        cur ^= 1;
    }
    // ---------------- fused tproj epilogue (aliases arena, after final barrier) ----------------
    auto xb  = (ushort_t (*)[136])(arena);
    auto dsx = (ushort_t (*)[136])(arena + 8704);
    long pbase = (long)b * NN + m0;        // 32 points
    {
        const float4* xg4 = (const float4*)(x + pbase * CC);
        #pragma unroll
        for (int rep = 0; rep < 2; ++rep) {
            int i = rep * 512 + t;          // 1024 float4
            float4 xv = xg4[i];
            int p = i >> 5, c4 = (i & 31) * 4;
            *(uint2*)&xb[p][c4] = make_uint2(pack2(xv.x, xv.y), pack2(xv.z, xv.w));
        }
    }
    __syncthreads();
    {
        int c = w * 16 + a;
        #pragma unroll
        for (int ms = 0; ms < 2; ++ms)
            #pragma unroll
            for (int r = 0; r < 4; ++r) {
                int ml = ms * 16 + g * 4 + r;
                dsx[ml][c] = bf16r(bf16tof(xb[ml][c]) - acc[ms][r]);
            }
    }
    __syncthreads();
    {
        int ph = w & 1, fh = w >> 1;
        s16x8 aF[4];
        #pragma unroll
        for (int ki = 0; ki < 4; ++ki)
            aF[ki] = *(const s16x8*)&dsx[ph * 16 + a][ki * 32 + g * 8];
        #pragma unroll
        for (int oi = 0; oi < 2; ++oi) {
            int ot = fh * 2 + oi;
            f32x4 ac = (f32x4){0.f, 0.f, 0.f, 0.f};
            #pragma unroll
            for (int ki = 0; ki < 4; ++ki) {
                s16x8 bF = *(const s16x8*)(Wtb + ((long)(ot * 16 + a)) * CC + ki * 32 + g * 8);
                ac = __builtin_amdgcn_mfma_f32_16x16x32_bf16(aF[ki], bF, ac, 0, 0, 0);
            }
            int o = ot * 16 + a;
            float sc = g1[o] * rsqrtf(v1[o] + 1e-5f);
            float mm = m1[o], bb = b1[o], bo = bt[o];
            #pragma unroll
            for (int r = 0; r < 4; ++r) {
                int p = ph * 16 + g * 4 + r;
                float tv = ((ac[r] + bo) - mm) * sc + bb;
                tv = fmaxf(tv, 0.f);
                hb[(pbase + p) * CC + o] = bf16r(bf16tof(xb[p][o]) + tv);
            }
        }
    }
}

// ---------------- kernel 5: MFMA fused FF (XCD-swizzled), double-buffered weight chunks ----------------
__global__ __launch_bounds__(256) void k_ff(
        const ushort_t* __restrict__ hb, const ushort_t* __restrict__ W1b,
        const ushort_t* __restrict__ W2b,
        const float* __restrict__ bf1, const float* __restrict__ bf2,
        const float* __restrict__ g2, const float* __restrict__ b2,
        const float* __restrict__ m2, const float* __restrict__ v2,
        float* __restrict__ out) {
    __shared__ ushort_t hs[32][136];
    __shared__ ushort_t w1s[2][64][128];
    __shared__ ushort_t w2s[2][128][64];
    __shared__ ushort_t fss[32][72];
    long pbase = (long)(blockIdx.x & 7) * NN + (blockIdx.x >> 3) * 32;
    int t = threadIdx.x;
    int l = t & 63, wid = t >> 6;
    int ph = wid & 1, fh = wid >> 1;
    int lr = l & 15, lg = l >> 4;
    for (int i = t; i < 512; i += BDIM) {
        int r = i >> 4, c0 = (i & 15) * 8;
        *(uint4*)&hs[r][c0] = *(const uint4*)(hb + (pbase + r) * CC + c0);
    }
    #pragma unroll
    for (int rep = 0; rep < 4; ++rep) {
        int i = rep * BDIM + t;
        int r = i >> 4, c0 = (i & 15) * 8;
        *(uint4*)&w1s[0][r][c0 ^ ((r & 7) * 8)] = *(const uint4*)(W1b + (long)r * CC + c0);
    }
    #pragma unroll
    for (int rep = 0; rep < 4; ++rep) {
        int i = rep * BDIM + t;
        int r = i >> 3, c0 = (i & 7) * 8;
        *(uint4*)&w2s[0][r][c0 ^ ((r & 7) * 8)] = *(const uint4*)(W2b + (long)r * FF + c0);
    }
    __syncthreads();
    s16x8 hA[4];
    #pragma unroll
    for (int ki = 0; ki < 4; ++ki)
        hA[ki] = *(const s16x8*)&hs[ph * 16 + lr][ki * 32 + lg * 8];
    f32x4 acc2[4];
    #pragma unroll
    for (int i = 0; i < 4; ++i) acc2[i] = (f32x4){0.f, 0.f, 0.f, 0.f};

    int cur = 0;
    uint4 wrg0, wrg1, wrg2, wrg3, wrg4, wrg5, wrg6, wrg7;
    for (int fc = 0; fc < 8; ++fc) {
        if (fc) __syncthreads();
        int f0 = fc * 64;
        if (fc < 7) {
            int f0n = f0 + 64;
            int r1 = t >> 4, c1 = (t & 15) * 8;
            int r2 = t >> 3, c2 = (t & 7) * 8;
            wrg0 = *(const uint4*)(W1b + (long)(f0n + r1) * CC + c1);
            wrg1 = *(const uint4*)(W1b + (long)(f0n + 16 + r1) * CC + c1);
            wrg2 = *(const uint4*)(W1b + (long)(f0n + 32 + r1) * CC + c1);
            wrg3 = *(const uint4*)(W1b + (long)(f0n + 48 + r1) * CC + c1);
            wrg4 = *(const uint4*)(W2b + (long)r2 * FF + f0n + c2);
            wrg5 = *(const uint4*)(W2b + (long)(32 + r2) * FF + f0n + c2);
            wrg6 = *(const uint4*)(W2b + (long)(64 + r2) * FF + f0n + c2);
            wrg7 = *(const uint4*)(W2b + (long)(96 + r2) * FF + f0n + c2);
        }
        #pragma unroll
        for (int fi = 0; fi < 2; ++fi) {
            int ft = fh * 2 + fi;
            int row = ft * 16 + lr;
            f32x4 a1 = (f32x4){0.f, 0.f, 0.f, 0.f};
            #pragma unroll
            for (int ki = 0; ki < 4; ++ki) {
                int col = ki * 32 + lg * 8;
                s16x8 bfr = *(const s16x8*)&w1s[cur][row][col ^ ((row & 7) * 8)];
                a1 = __builtin_amdgcn_mfma_f32_16x16x32_bf16(hA[ki], bfr, a1, 0, 0, 0);
            }
            float bias = bf1[f0 + ft * 16 + lr];
            #pragma unroll
            for (int r = 0; r < 4; ++r) {
                float vv = fmaxf(a1[r] + bias, 0.f);
                fss[ph * 16 + lg * 4 + r][ft * 16 + lr] = bf16r(vv);
            }
        }
        __syncthreads();
        #pragma unroll
        for (int k2 = 0; k2 < 2; ++k2) {
            s16x8 afr = *(const s16x8*)&fss[ph * 16 + lr][k2 * 32 + lg * 8];
            #pragma unroll
            for (int oi = 0; oi < 4; ++oi) {
                int ot = fh * 4 + oi;
                int row = ot * 16 + lr;
                int col = k2 * 32 + lg * 8;
                s16x8 bfr = *(const s16x8*)&w2s[cur][row][col ^ ((row & 7) * 8)];
                acc2[oi] = __builtin_amdgcn_mfma_f32_16x16x32_bf16(afr, bfr, acc2[oi], 0, 0, 0);
            }
        }
        if (fc < 7) {
            int nb = cur ^ 1;
            int r1 = t >> 4, c1 = (t & 15) * 8;
            int r2 = t >> 3, c2 = (t & 7) * 8;
            *(uint4*)&w1s[nb][r1][c1 ^ ((r1 & 7) * 8)] = wrg0;
            *(uint4*)&w1s[nb][16 + r1][c1 ^ ((r1 & 7) * 8)] = wrg1;
            *(uint4*)&w1s[nb][32 + r1][c1 ^ ((r1 & 7) * 8)] = wrg2;
            *(uint4*)&w1s[nb][48 + r1][c1 ^ ((r1 & 7) * 8)] = wrg3;
            *(uint4*)&w2s[nb][r2][c2 ^ ((r2 & 7) * 8)] = wrg4;
            *(uint4*)&w2s[nb][32 + r2][c2 ^ (((32 + r2) & 7) * 8)] = wrg5;
            *(uint4*)&w2s[nb][64 + r2][c2 ^ (((64 + r2) & 7) * 8)] = wrg6;
            *(uint4*)&w2s[nb][96 + r2][c2 ^ (((96 + r2) & 7) * 8)] = wrg7;
            cur = nb;
        }
    }
    #pragma unroll
    for (int oi = 0; oi < 4; ++oi) {
        int o = (fh * 4 + oi) * 16 + lr;
        float sc = g2[o] * rsqrtf(v2[o] + 1e-5f);
        float mm = m2[o], bb = b2[o], bias2 = bf2[o];
        #pragma unroll
        for (int r = 0; r < 4; ++r) {
            int p = ph * 16 + lg * 4 + r;
            float val = bf16tof(hs[p][o]) + acc2[oi][r] + bias2;
            out[(pbase + p) * CC + o] = (val - mm) * sc + bb;
        }
    }
}

extern "C" void kernel_launch(void* const* d_in, const int* in_sizes, int n_in,
                              void* d_out, int out_size, void* d_ws, size_t ws_size,
                              hipStream_t stream) {
    const float* x   = (const float*)d_in[0];
    const float* Wq  = (const float*)d_in[1];
    const float* Wk  = (const float*)d_in[2];
    const float* Wv  = (const float*)d_in[3];
    const float* bv  = (const float*)d_in[4];
    const float* Wt  = (const float*)d_in[5];
    const float* bt  = (const float*)d_in[6];
    const float* g1  = (const float*)d_in[7];
    const float* b1  = (const float*)d_in[8];
    const float* m1  = (const float*)d_in[9];
    const float* v1  = (const float*)d_in[10];
    const float* W1  = (const float*)d_in[11];
    const float* bf1 = (const float*)d_in[12];
    const float* W2  = (const float*)d_in[13];
    const float* bf2 = (const float*)d_in[14];
    const float* g2  = (const float*)d_in[15];
    const float* b2  = (const float*)d_in[16];
    const float* m2  = (const float*)d_in[17];
    const float* v2  = (const float*)d_in[18];
    float* out = (float*)d_out;

    float* ws  = (float*)d_ws;
    float* rin = ws;                            // NPTS
    ushort_t* qg   = (ushort_t*)(rin + NPTS);   // NPTS*DD
    ushort_t* kg   = qg + (long)NPTS * DD;      // NPTS*DD
    ushort_t* vTg  = kg + (long)NPTS * DD;      // NPTS*CC ([b][c][n])
    ushort_t* hbuf = vTg + (long)NPTS * CC;     // NPTS*CC
    ushort_t* W1b  = hbuf + (long)NPTS * CC;    // FF*CC
    ushort_t* W2b  = W1b + FF * CC;             // FF*CC
    ushort_t* Wb   = W2b + FF * CC;             // 192*CC (Wq|Wk|Wv)
    ushort_t* Wtb  = Wb + 192 * CC;             // CC*CC

    k_cvt_all<<<168, BDIM, 0, stream>>>(W1, W2, Wq, Wk, Wv, Wt, W1b);
    k_proj<<<NPTS / 32, BDIM, 0, stream>>>(x, Wb, bv, qg, kg, vTg);
    k_rowstats<<<8 * (NN / 64), BDIM, 0, stream>>>(qg, kg, rin);
    k_pv<<<8 * (NN / 32), 512, 0, stream>>>(qg, kg, vTg, rin,
                                            x, Wtb, bt, g1, b1, m1, v1, hbuf);
    k_ff<<<NPTS / 32, BDIM, 0, stream>>>(hbuf, W1b, W2b, bf1, bf2, g2, b2, m2, v2, out);
}

// Round 20
// 70.243 us; speedup vs baseline: 1.0400x; 1.0400x over previous
//
#include <hip/hip_runtime.h>
#include <hip/hip_bf16.h>

#define BDIM 256
#define NPTS (8 * 2048)           // B*N
#define CC 128
#define DD 32
#define FF 512
#define NN 2048
#define SCALE 0.08838834764831845f   // 1/sqrt(128)

typedef float f32x4 __attribute__((ext_vector_type(4)));
typedef short s16x8 __attribute__((ext_vector_type(8)));
typedef unsigned short ushort_t;

__device__ __forceinline__ ushort_t bf16r(float x) {
    __hip_bfloat16 h = __float2bfloat16(x);
    return *reinterpret_cast<ushort_t*>(&h);
}
__device__ __forceinline__ float bf16tof(ushort_t u) {
    unsigned v = ((unsigned)u) << 16;
    return *reinterpret_cast<float*>(&v);
}
__device__ __forceinline__ unsigned pack2(float a, float b) {
    return ((unsigned)bf16r(b) << 16) | (unsigned)bf16r(a);
}

// ---------------- kernel 0: all weights f32 -> bf16, one launch ----------------
__global__ void k_cvt_all(const float* __restrict__ W1, const float* __restrict__ W2,
                          const float* __restrict__ Wq, const float* __restrict__ Wk,
                          const float* __restrict__ Wv, const float* __restrict__ Wt,
                          ushort_t* __restrict__ dst) {
    int i = blockIdx.x * BDIM + threadIdx.x;     // float4 index, 43008 total
    const float* src; int off;
    if (i < 16384)      { src = W1; off = 0; }
    else if (i < 32768) { src = W2; off = 16384; }
    else if (i < 33792) { src = Wq; off = 32768; }
    else if (i < 34816) { src = Wk; off = 33792; }
    else if (i < 38912) { src = Wv; off = 34816; }
    else                { src = Wt; off = 38912; }
    float4 v = ((const float4*)src)[i - off];
    *(uint2*)(dst + (long)i * 4) = make_uint2(pack2(v.x, v.y), pack2(v.z, v.w));
}

// ---------------- kernel 1: MFMA q/k/vT projection (XCD-swizzled: b = bid&7) ----------------
__global__ __launch_bounds__(256) void k_proj(
        const float* __restrict__ x, const ushort_t* __restrict__ Wb,
        const float* __restrict__ bv,
        ushort_t* __restrict__ qg, ushort_t* __restrict__ kg,
        ushort_t* __restrict__ vTg) {
    __shared__ ushort_t xs[32][136];
    __shared__ ushort_t qks[32][72];    // q cols 0-31, k cols 32-63
    __shared__ ushort_t vs[32][136];
    int b = blockIdx.x & 7;
    int n0 = (blockIdx.x >> 3) * 32;
    long base = (long)b * NN + n0;
    int t = threadIdx.x, w = t >> 6, l = t & 63, a = l & 15, g = l >> 4;
    {
        const float4* xg4 = (const float4*)(x + base * CC);
        #pragma unroll
        for (int rep = 0; rep < 4; ++rep) {
            int i = rep * BDIM + t;
            float4 v4 = xg4[i];
            int p = i >> 5, c4 = (i & 31) * 4;
            *(uint2*)&xs[p][c4] = make_uint2(pack2(v4.x, v4.y), pack2(v4.z, v4.w));
        }
    }
    s16x8 bF[3][4];
    #pragma unroll
    for (int ct = 0; ct < 3; ++ct) {
        int ctg = w * 3 + ct;
        #pragma unroll
        for (int ki = 0; ki < 4; ++ki)
            bF[ct][ki] = *(const s16x8*)(Wb + ((long)(ctg * 16 + a)) * CC + ki * 32 + g * 8);
    }
    __syncthreads();
    #pragma unroll
    for (int rt = 0; rt < 2; ++rt) {
        s16x8 aF[4];
        #pragma unroll
        for (int ki = 0; ki < 4; ++ki)
            aF[ki] = *(const s16x8*)&xs[rt * 16 + a][ki * 32 + g * 8];
        #pragma unroll
        for (int ct = 0; ct < 3; ++ct) {
            f32x4 acc = (f32x4){0.f, 0.f, 0.f, 0.f};
            #pragma unroll
            for (int ki = 0; ki < 4; ++ki)
                acc = __builtin_amdgcn_mfma_f32_16x16x32_bf16(aF[ki], bF[ct][ki], acc, 0, 0, 0);
            int ctg = w * 3 + ct;
            int oc = ctg * 16 + a;
            float bias = (oc >= 64) ? bv[oc - 64] : 0.f;
            #pragma unroll
            for (int r = 0; r < 4; ++r) {
                int p = rt * 16 + g * 4 + r;
                float val = acc[r] + bias;
                if (oc < 64) qks[p][oc] = bf16r(val);
                else         vs[p][oc - 64] = bf16r(val);
            }
        }
    }
    __syncthreads();
    {
        int p = t >> 3, c = (t & 7) * 4;
        *(uint2*)(qg + (base + p) * DD + c) = *(const uint2*)&qks[p][c];
        *(uint2*)(kg + (base + p) * DD + c) = *(const uint2*)&qks[p][32 + c];
    }
    #pragma unroll
    for (int rep = 0; rep < 2; ++rep) {
        int i = rep * BDIM + t;
        int c = i & 127, nch = i >> 7;
        int p0 = nch * 8;
        uint4 r;
        r.x = (unsigned)vs[p0+0][c] | ((unsigned)vs[p0+1][c] << 16);
        r.y = (unsigned)vs[p0+2][c] | ((unsigned)vs[p0+3][c] << 16);
        r.z = (unsigned)vs[p0+4][c] | ((unsigned)vs[p0+5][c] << 16);
        r.w = (unsigned)vs[p0+6][c] | ((unsigned)vs[p0+7][c] << 16);
        *(uint4*)(vTg + ((long)(b * CC + c)) * NN + n0 + p0) = r;
    }
}

// ---------------- kernel 2: MFMA row softmax sums (XCD-swizzled: b = bid&7) ----------------
__global__ __launch_bounds__(256) void k_rowstats(
        const ushort_t* __restrict__ qg, const ushort_t* __restrict__ kg,
        float* __restrict__ rowinv) {
    __shared__ float ps[4][64];
    int b = blockIdx.x & 7;
    int nt = (blockIdx.x >> 3) * 64;
    int t = threadIdx.x, w = t >> 6, l = t & 63, a = l & 15, g = l >> 4;
    s16x8 qA[4];
    #pragma unroll
    for (int s = 0; s < 4; ++s)
        qA[s] = *(const s16x8*)(qg + ((long)(b * NN + nt + s*16 + a)) * DD + g*8);
    float sm[16];
    #pragma unroll
    for (int i = 0; i < 16; ++i) sm[i] = 0.f;
    s16x8 kB = *(const s16x8*)(kg + ((long)(b * NN + w * 16 + a)) * DD + g*8);
    for (int it = 0; it < 32; ++it) {
        s16x8 kBn;
        if (it < 31)
            kBn = *(const s16x8*)(kg + ((long)(b * NN + ((it+1)*4 + w)*16 + a)) * DD + g*8);
        #pragma unroll
        for (int s = 0; s < 4; ++s) {
            f32x4 D = (f32x4){0.f, 0.f, 0.f, 0.f};
            D = __builtin_amdgcn_mfma_f32_16x16x32_bf16(qA[s], kB, D, 0, 0, 0);
            #pragma unroll
            for (int r = 0; r < 4; ++r)
                sm[s * 4 + r] += __expf(D[r] * SCALE);
        }
        kB = kBn;
    }
    #pragma unroll
    for (int off = 1; off < 16; off <<= 1)
        #pragma unroll
        for (int ix = 0; ix < 16; ++ix)
            sm[ix] += __shfl_xor(sm[ix], off, 64);
    if (a == 0) {
        #pragma unroll
        for (int s = 0; s < 4; ++s)
            #pragma unroll
            for (int r = 0; r < 4; ++r)
                ps[w][s * 16 + g * 4 + r] = sm[s * 4 + r];
    }
    __syncthreads();
    if (t < 64) {
        float S = ps[0][t] + ps[1][t] + ps[2][t] + ps[3][t];
        rowinv[(long)b * NN + nt + t] = 1.f / S;
    }
}

// ---------------- kernel 3: MFMA PV (XCD-swizzled, staged-vT dbuf) + tproj epilogue ----------------
// grid: 512 blocks x 512 thr. LDS 41472 B: vTs[2][128][72] @0 | pT[32][72] @36864.
// q/rowinv/K direct register prefetch; vT staged coalesced (write-after-PV, T14).
__global__ __launch_bounds__(512) void k_pv(
        const ushort_t* __restrict__ qg, const ushort_t* __restrict__ kg,
        const ushort_t* __restrict__ vTg, const float* __restrict__ rowinv,
        const float* __restrict__ x, const ushort_t* __restrict__ Wtb,
        const float* __restrict__ bt,
        const float* __restrict__ g1, const float* __restrict__ b1,
        const float* __restrict__ m1, const float* __restrict__ v1,
        ushort_t* __restrict__ hb) {
    __shared__ __align__(16) char arena[41472];
    auto vTs = (ushort_t (*)[128][72])(arena);          // [2][128][72]
    auto pT  = (ushort_t (*)[72])(arena + 36864);       // [32][72]
    int b = blockIdx.x & 7;
    int m0 = (blockIdx.x >> 3) * 32;
    int t = threadIdx.x, w = t >> 6, l = t & 63, a = l & 15, g = l >> 4;
    int nsub = w & 3, msub = w >> 2;
    const ushort_t* vTb = vTg + (long)b * CC * NN;
    // per-wave constant K frag
    s16x8 kf = *(const s16x8*)(kg + ((long)(b * NN + m0 + msub * 16 + a)) * DD + g * 8);
    // direct-prefetch bases
    const ushort_t* qrow = qg + ((long)(b * NN + nsub * 16 + a)) * DD + g * 8;
    const float*    rrow = rowinv + (long)b * NN + nsub * 16 + g * 4;
    // vT staging indices: 2 reps x (64 rows x 8 uint4)
    int sc = t >> 3;            // row 0..63 (rep adds +64)
    int sj = (t & 7) * 8;       // ushort col offset
    // prologue: stage tile 0, load E-frags for tile 0
    s16x8 qf_c = *(const s16x8*)qrow;
    float4 rr_c = *(const float4*)rrow;
    {
        uint4 v0 = *(const uint4*)(vTb + (long)sc * NN + sj);
        uint4 v1 = *(const uint4*)(vTb + (long)(64 + sc) * NN + sj);
        *(uint4*)&vTs[0][sc][sj] = v0;
        *(uint4*)&vTs[0][64 + sc][sj] = v1;
    }
    f32x4 acc[2];
    acc[0] = (f32x4){0.f, 0.f, 0.f, 0.f};
    acc[1] = (f32x4){0.f, 0.f, 0.f, 0.f};
    int cur = 0;
    __syncthreads();                       // vTs[0] ready
    s16x8 qf_n; float4 rr_n; uint4 vsr0, vsr1;
    for (int it = 0; it < 32; ++it) {
        long ntn = (long)(it + 1) * 64;
        if (it < 31) {                     // issue tile it+1 loads (land during E+PV)
            vsr0 = *(const uint4*)(vTb + (long)sc * NN + ntn + sj);
            vsr1 = *(const uint4*)(vTb + (long)(64 + sc) * NN + ntn + sj);
            qf_n = *(const s16x8*)(qrow + ntn * DD);
            rr_n = *(const float4*)(rrow + ntn);
        }
        // E phase on tile it -> pT
        {
            f32x4 e = (f32x4){0.f, 0.f, 0.f, 0.f};
            e = __builtin_amdgcn_mfma_f32_16x16x32_bf16(qf_c, kf, e, 0, 0, 0);
            float p0 = __expf(e[0] * SCALE) * rr_c.x;
            float p1 = __expf(e[1] * SCALE) * rr_c.y;
            float p2 = __expf(e[2] * SCALE) * rr_c.z;
            float p3 = __expf(e[3] * SCALE) * rr_c.w;
            *(uint2*)&pT[msub * 16 + a][nsub * 16 + g * 4] =
                make_uint2(pack2(p0, p1), pack2(p2, p3));
        }
        __syncthreads();                   // pT ready (vTs[cur] still valid)
        // PV phase on tile it
        #pragma unroll
        for (int k2 = 0; k2 < 2; ++k2) {
            s16x8 A0 = *(const s16x8*)&pT[a][k2 * 32 + g * 8];
            s16x8 A1 = *(const s16x8*)&pT[16 + a][k2 * 32 + g * 8];
            s16x8 Bf = *(const s16x8*)&vTs[cur][w * 16 + a][k2 * 32 + g * 8];
            acc[0] = __builtin_amdgcn_mfma_f32_16x16x32_bf16(A0, Bf, acc[0], 0, 0, 0);
            acc[1] = __builtin_amdgcn_mfma_f32_16x16x32_bf16(A1, Bf, acc[1], 0, 0, 0);
        }
        if (it < 31) {                     // write staged tile into other buffer
            *(uint4*)&vTs[cur ^ 1][sc][sj] = vsr0;
            *(uint4*)&vTs[cur ^ 1][64 + sc][sj] = vsr1;
        }
        qf_c = qf_n; rr_c = rr_n;
        __syncthreads();                   // vTs[cur^1] ready; pT consumed
        cur ^= 1;
    }
    // ---------------- fused tproj epilogue (aliases arena, after final barrier) ----------------
    auto xb  = (ushort_t (*)[136])(arena);
    auto dsx = (ushort_t (*)[136])(arena + 8704);
    long pbase = (long)b * NN + m0;        // 32 points
    {
        const float4* xg4 = (const float4*)(x + pbase * CC);
        #pragma unroll
        for (int rep = 0; rep < 2; ++rep) {
            int i = rep * 512 + t;          // 1024 float4
            float4 xv = xg4[i];
            int p = i >> 5, c4 = (i & 31) * 4;
            *(uint2*)&xb[p][c4] = make_uint2(pack2(xv.x, xv.y), pack2(xv.z, xv.w));
        }
    }
    __syncthreads();
    {
        int c = w * 16 + a;
        #pragma unroll
        for (int ms = 0; ms < 2; ++ms)
            #pragma unroll
            for (int r = 0; r < 4; ++r) {
                int ml = ms * 16 + g * 4 + r;
                dsx[ml][c] = bf16r(bf16tof(xb[ml][c]) - acc[ms][r]);
            }
    }
    __syncthreads();
    {
        int ph = w & 1, fh = w >> 1;
        s16x8 aF[4];
        #pragma unroll
        for (int ki = 0; ki < 4; ++ki)
            aF[ki] = *(const s16x8*)&dsx[ph * 16 + a][ki * 32 + g * 8];
        #pragma unroll
        for (int oi = 0; oi < 2; ++oi) {
            int ot = fh * 2 + oi;
            f32x4 ac = (f32x4){0.f, 0.f, 0.f, 0.f};
            #pragma unroll
            for (int ki = 0; ki < 4; ++ki) {
                s16x8 bF = *(const s16x8*)(Wtb + ((long)(ot * 16 + a)) * CC + ki * 32 + g * 8);
                ac = __builtin_amdgcn_mfma_f32_16x16x32_bf16(aF[ki], bF, ac, 0, 0, 0);
            }
            int o = ot * 16 + a;
            float sc = g1[o] * rsqrtf(v1[o] + 1e-5f);
            float mm = m1[o], bb = b1[o], bo = bt[o];
            #pragma unroll
            for (int r = 0; r < 4; ++r) {
                int p = ph * 16 + g * 4 + r;
                float tv = ((ac[r] + bo) - mm) * sc + bb;
                tv = fmaxf(tv, 0.f);
                hb[(pbase + p) * CC + o] = bf16r(bf16tof(xb[p][o]) + tv);
            }
        }
    }
}

// ---------------- kernel 5: MFMA fused FF (XCD-swizzled), double-buffered weight chunks ----------------
__global__ __launch_bounds__(256) void k_ff(
        const ushort_t* __restrict__ hb, const ushort_t* __restrict__ W1b,
        const ushort_t* __restrict__ W2b,
        const float* __restrict__ bf1, const float* __restrict__ bf2,
        const float* __restrict__ g2, const float* __restrict__ b2,
        const float* __restrict__ m2, const float* __restrict__ v2,
        float* __restrict__ out) {
    __shared__ ushort_t hs[32][136];
    __shared__ ushort_t w1s[2][64][128];
    __shared__ ushort_t w2s[2][128][64];
    __shared__ ushort_t fss[32][72];
    long pbase = (long)(blockIdx.x & 7) * NN + (blockIdx.x >> 3) * 32;
    int t = threadIdx.x;
    int l = t & 63, wid = t >> 6;
    int ph = wid & 1, fh = wid >> 1;
    int lr = l & 15, lg = l >> 4;
    for (int i = t; i < 512; i += BDIM) {
        int r = i >> 4, c0 = (i & 15) * 8;
        *(uint4*)&hs[r][c0] = *(const uint4*)(hb + (pbase + r) * CC + c0);
    }
    #pragma unroll
    for (int rep = 0; rep < 4; ++rep) {
        int i = rep * BDIM + t;
        int r = i >> 4, c0 = (i & 15) * 8;
        *(uint4*)&w1s[0][r][c0 ^ ((r & 7) * 8)] = *(const uint4*)(W1b + (long)r * CC + c0);
    }
    #pragma unroll
    for (int rep = 0; rep < 4; ++rep) {
        int i = rep * BDIM + t;
        int r = i >> 3, c0 = (i & 7) * 8;
        *(uint4*)&w2s[0][r][c0 ^ ((r & 7) * 8)] = *(const uint4*)(W2b + (long)r * FF + c0);
    }
    __syncthreads();
    s16x8 hA[4];
    #pragma unroll
    for (int ki = 0; ki < 4; ++ki)
        hA[ki] = *(const s16x8*)&hs[ph * 16 + lr][ki * 32 + lg * 8];
    f32x4 acc2[4];
    #pragma unroll
    for (int i = 0; i < 4; ++i) acc2[i] = (f32x4){0.f, 0.f, 0.f, 0.f};

    int cur = 0;
    uint4 wrg0, wrg1, wrg2, wrg3, wrg4, wrg5, wrg6, wrg7;
    for (int fc = 0; fc < 8; ++fc) {
        if (fc) __syncthreads();
        int f0 = fc * 64;
        if (fc < 7) {
            int f0n = f0 + 64;
            int r1 = t >> 4, c1 = (t & 15) * 8;
            int r2 = t >> 3, c2 = (t & 7) * 8;
            wrg0 = *(const uint4*)(W1b + (long)(f0n + r1) * CC + c1);
            wrg1 = *(const uint4*)(W1b + (long)(f0n + 16 + r1) * CC + c1);
            wrg2 = *(const uint4*)(W1b + (long)(f0n + 32 + r1) * CC + c1);
            wrg3 = *(const uint4*)(W1b + (long)(f0n + 48 + r1) * CC + c1);
            wrg4 = *(const uint4*)(W2b + (long)r2 * FF + f0n + c2);
            wrg5 = *(const uint4*)(W2b + (long)(32 + r2) * FF + f0n + c2);
            wrg6 = *(const uint4*)(W2b + (long)(64 + r2) * FF + f0n + c2);
            wrg7 = *(const uint4*)(W2b + (long)(96 + r2) * FF + f0n + c2);
        }
        #pragma unroll
        for (int fi = 0; fi < 2; ++fi) {
            int ft = fh * 2 + fi;
            int row = ft * 16 + lr;
            f32x4 a1 = (f32x4){0.f, 0.f, 0.f, 0.f};
            #pragma unroll
            for (int ki = 0; ki < 4; ++ki) {
                int col = ki * 32 + lg * 8;
                s16x8 bfr = *(const s16x8*)&w1s[cur][row][col ^ ((row & 7) * 8)];
                a1 = __builtin_amdgcn_mfma_f32_16x16x32_bf16(hA[ki], bfr, a1, 0, 0, 0);
            }
            float bias = bf1[f0 + ft * 16 + lr];
            #pragma unroll
            for (int r = 0; r < 4; ++r) {
                float vv = fmaxf(a1[r] + bias, 0.f);
                fss[ph * 16 + lg * 4 + r][ft * 16 + lr] = bf16r(vv);
            }
        }
        __syncthreads();
        #pragma unroll
        for (int k2 = 0; k2 < 2; ++k2) {
            s16x8 afr = *(const s16x8*)&fss[ph * 16 + lr][k2 * 32 + lg * 8];
            #pragma unroll
            for (int oi = 0; oi < 4; ++oi) {
                int ot = fh * 4 + oi;
                int row = ot * 16 + lr;
                int col = k2 * 32 + lg * 8;
                s16x8 bfr = *(const s16x8*)&w2s[cur][row][col ^ ((row & 7) * 8)];
                acc2[oi] = __builtin_amdgcn_mfma_f32_16x16x32_bf16(afr, bfr, acc2[oi], 0, 0, 0);
            }
        }
        if (fc < 7) {
            int nb = cur ^ 1;
            int r1 = t >> 4, c1 = (t & 15) * 8;
            int r2 = t >> 3, c2 = (t & 7) * 8;
            *(uint4*)&w1s[nb][r1][c1 ^ ((r1 & 7) * 8)] = wrg0;
            *(uint4*)&w1s[nb][16 + r1][c1 ^ ((r1 & 7) * 8)] = wrg1;
            *(uint4*)&w1s[nb][32 + r1][c1 ^ ((r1 & 7) * 8)] = wrg2;
            *(uint4*)&w1s[nb][48 + r1][c1 ^ ((r1 & 7) * 8)] = wrg3;
            *(uint4*)&w2s[nb][r2][c2 ^ ((r2 & 7) * 8)] = wrg4;
            *(uint4*)&w2s[nb][32 + r2][c2 ^ (((32 + r2) & 7) * 8)] = wrg5;
            *(uint4*)&w2s[nb][64 + r2][c2 ^ (((64 + r2) & 7) * 8)] = wrg6;
            *(uint4*)&w2s[nb][96 + r2][c2 ^ (((96 + r2) & 7) * 8)] = wrg7;
            cur = nb;
        }
    }
    #pragma unroll
    for (int oi = 0; oi < 4; ++oi) {
        int o = (fh * 4 + oi) * 16 + lr;
        float sc = g2[o] * rsqrtf(v2[o] + 1e-5f);
        float mm = m2[o], bb = b2[o], bias2 = bf2[o];
        #pragma unroll
        for (int r = 0; r < 4; ++r) {
            int p = ph * 16 + lg * 4 + r;
            float val = bf16tof(hs[p][o]) + acc2[oi][r] + bias2;
            out[(pbase + p) * CC + o] = (val - mm) * sc + bb;
        }
    }
}

extern "C" void kernel_launch(void* const* d_in, const int* in_sizes, int n_in,
                              void* d_out, int out_size, void* d_ws, size_t ws_size,
                              hipStream_t stream) {
    const float* x   = (const float*)d_in[0];
    const float* Wq  = (const float*)d_in[1];
    const float* Wk  = (const float*)d_in[2];
    const float* Wv  = (const float*)d_in[3];
    const float* bv  = (const float*)d_in[4];
    const float* Wt  = (const float*)d_in[5];
    const float* bt  = (const float*)d_in[6];
    const float* g1  = (const float*)d_in[7];
    const float* b1  = (const float*)d_in[8];
    const float* m1  = (const float*)d_in[9];
    const float* v1  = (const float*)d_in[10];
    const float* W1  = (const float*)d_in[11];
    const float* bf1 = (const float*)d_in[12];
    const float* W2  = (const float*)d_in[13];
    const float* bf2 = (const float*)d_in[14];
    const float* g2  = (const float*)d_in[15];
    const float* b2  = (const float*)d_in[16];
    const float* m2  = (const float*)d_in[17];
    const float* v2  = (const float*)d_in[18];
    float* out = (float*)d_out;

    float* ws  = (float*)d_ws;
    float* rin = ws;                            // NPTS
    ushort_t* qg   = (ushort_t*)(rin + NPTS);   // NPTS*DD
    ushort_t* kg   = qg + (long)NPTS * DD;      // NPTS*DD
    ushort_t* vTg  = kg + (long)NPTS * DD;      // NPTS*CC ([b][c][n])
    ushort_t* hbuf = vTg + (long)NPTS * CC;     // NPTS*CC
    ushort_t* W1b  = hbuf + (long)NPTS * CC;    // FF*CC
    ushort_t* W2b  = W1b + FF * CC;             // FF*CC
    ushort_t* Wb   = W2b + FF * CC;             // 192*CC (Wq|Wk|Wv)
    ushort_t* Wtb  = Wb + 192 * CC;             // CC*CC

    k_cvt_all<<<168, BDIM, 0, stream>>>(W1, W2, Wq, Wk, Wv, Wt, W1b);
    k_proj<<<NPTS / 32, BDIM, 0, stream>>>(x, Wb, bv, qg, kg, vTg);
    k_rowstats<<<8 * (NN / 64), BDIM, 0, stream>>>(qg, kg, rin);
    k_pv<<<8 * (NN / 32), 512, 0, stream>>>(qg, kg, vTg, rin,
                                            x, Wtb, bt, g1, b1, m1, v1, hbuf);
    k_ff<<<NPTS / 32, BDIM, 0, stream>>>(hbuf, W1b, W2b, bf1, bf2, g2, b2, m2, v2, out);
}